// Round 14
// baseline (98.720 us; speedup 1.0000x reference)
//
#include <hip/hip_runtime.h>

#define ROWS 16384                 // points per side
#define PTS_TOTAL 32768
#define NSM_BLK 256                // softmin blocks, 128 rows each, 8 waves

#define LOG2E 1.4426950408889634f
#define LN2   0.6931471805599453f
#define NEG_LOG2M (-12.0f)              /* -log2(4096) */
#define EPS1LNM 8.317766166719343e-4f   /* eps1 * ln(4096) */

typedef _Float16 h2 __attribute__((ext_vector_type(2)));
typedef _Float16 v8h __attribute__((ext_vector_type(8)));
typedef float f32x4 __attribute__((ext_vector_type(4)));

__device__ inline float fexp2(float x) { return __builtin_amdgcn_exp2f(x); }
__device__ inline float flog2(float x) { return __builtin_amdgcn_logf(x); }

__device__ inline unsigned fenc(float f) {
  unsigned u = __float_as_uint(f);
  return (u & 0x80000000u) ? ~u : (u | 0x80000000u);
}
__device__ inline float fdec(unsigned u) {
  return (u & 0x80000000u) ? __uint_as_float(u & 0x7fffffffu)
                           : __uint_as_float(~u);
}
__device__ inline unsigned pkh2(float a, float b) {
  h2 hv; hv.x = (_Float16)a; hv.y = (_Float16)b;
  return __builtin_bit_cast(unsigned, hv);
}
__device__ inline v8h bcv8(uint4 u) { return __builtin_bit_cast(v8h, u); }

// ---- normalized features + squared norm -----------------------------------
__device__ inline float mkv(const float* __restrict__ p, float s, float* v) {
  v[0] = p[0] * s; v[1] = p[1] * s; v[2] = p[2] * s;
  v[3] = 0.1f * fminf(fmaxf(p[3], 0.0f), 1.0f);
  v[4] = 0.1f * fminf(fmaxf(p[4], 0.0f), 1.0f);
  v[5] = 0.1f * fminf(fmaxf(p[5], 0.0f), 1.0f);
  return v[0]*v[0] + v[1]*v[1] + v[2]*v[2] + v[3]*v[3] + v[4]*v[4] + v[5]*v[5];
}

// ---- Taylor softmin evaluation (eps0 regime); M in LDS --------------------
__device__ inline float taylor_f(const float* __restrict__ M, const float* v,
                                 float q, float eps0) {
  float sc2 = 2.0f * LOG2E / eps0;
  float p[6];
#pragma unroll
  for (int d = 0; d < 6; ++d) p[d] = v[d] * sc2;
  float t1 = 0.0f;
#pragma unroll
  for (int d = 0; d < 6; ++d) t1 += p[d] * M[1 + d];
  float t2 = 0.0f;
  int kk = 7;
#pragma unroll
  for (int d = 0; d < 6; ++d) {
#pragma unroll
    for (int e = d; e < 6; ++e) {
      float coef = (d == e) ? 1.0f : 2.0f;
      t2 += coef * p[d] * p[e] * M[kk];
      kk++;
    }
  }
  float S = M[0] + LN2 * t1 + (0.5f * LN2 * LN2) * t2;
  return q - eps0 * LN2 * flog2(S);
}

// ---- single-point 28-moment vector ----------------------------------------
__device__ inline void mom28(float* acc, float wgt, const float* v) {
  acc[0] = wgt;
  int kk = 1;
#pragma unroll
  for (int d = 0; d < 6; ++d) acc[kk++] = wgt * v[d];
#pragma unroll
  for (int d = 0; d < 6; ++d) {
    float wv = wgt * v[d];
#pragma unroll
    for (int e = d; e < 6; ++e) acc[kk++] = wv * v[e];
  }
}

// ---- block reduce of 28 floats -> global dst[0..27] -----------------------
__device__ inline void red28g(float* acc, float* __restrict__ dst,
                              float (*shf)[28], int t, int wave, int lane) {
#pragma unroll
  for (int off = 32; off > 0; off >>= 1) {
#pragma unroll
    for (int k = 0; k < 28; ++k) acc[k] += __shfl_xor(acc[k], off);
  }
  if (lane == 0) {
#pragma unroll
    for (int k = 0; k < 28; ++k) shf[wave][k] = acc[k];
  }
  __syncthreads();
  if (t < 28) dst[t] = (shf[0][t] + shf[1][t]) + (shf[2][t] + shf[3][t]);
}

// ---- redundant global s/eps0 from 128 max-partial sets --------------------
__device__ inline void se_from_rmax(const unsigned* __restrict__ RMAXu,
                                    unsigned (*shu)[13], float& s, float& eps0,
                                    int t, int wave, int lane) {
  int set = t & 127;   // halves duplicate a set; max is idempotent
  unsigned e[13];
#pragma unroll
  for (int k = 0; k < 13; ++k) e[k] = RMAXu[set * 16 + k];
#pragma unroll
  for (int off = 32; off > 0; off >>= 1) {
#pragma unroll
    for (int k = 0; k < 13; ++k) {
      unsigned o = (unsigned)__shfl_xor((int)e[k], off);
      e[k] = e[k] > o ? e[k] : o;
    }
  }
  if (lane == 0) {
#pragma unroll
    for (int k = 0; k < 13; ++k) shu[wave][k] = e[k];
  }
  __syncthreads();
  unsigned mm[13];
#pragma unroll
  for (int k = 0; k < 13; ++k) {
    unsigned v0 = shu[0][k] > shu[1][k] ? shu[0][k] : shu[1][k];
    unsigned v1 = shu[2][k] > shu[3][k] ? shu[2][k] : shu[3][k];
    mm[k] = v0 > v1 ? v0 : v1;
  }
  s = 1.0f / (sqrtf(fdec(mm[0])) + 1e-6f);
  eps0 = 0.0f;
#pragma unroll
  for (int k = 0; k < 6; ++k) {
    float dd = fdec(mm[1 + k]) + fdec(mm[7 + k]);
    eps0 += dd * dd;
  }
}

// ==== K1: per-block 13 max partials (LDS-staged vectorized loads) ==========
__global__ __launch_bounds__(256) void k1_max(
    const float* __restrict__ x, const float* __restrict__ y,
    float* __restrict__ w) {
  unsigned* BARC = (unsigned*)w;
  unsigned* RMAX = (unsigned*)w + 64;
  const int t = threadIdx.x, wave = t >> 6, lane = t & 63, bx = blockIdx.x;
  if (bx == 0 && t == 0) BARC[0] = 0u;     // collector counter for KC
  const int g0 = bx * 256;
  bool isx = g0 < ROWS;                    // 64 blocks per side; no straddle
  __shared__ float4 st[384];
  const float4* src =
      (const float4*)((isx ? x : y) + (size_t)(g0 & (ROWS - 1)) * 6);
  st[t] = src[t];
  if (t < 128) st[256 + t] = src[256 + t];
  __syncthreads();
  const float* sp = (const float*)st + t * 6;
  float d[6];
#pragma unroll
  for (int k = 0; k < 6; ++k) d[k] = sp[k];
  unsigned e[13];
  e[0] = fenc(d[0] * d[0] + d[1] * d[1] + d[2] * d[2]);
#pragma unroll
  for (int k = 0; k < 6; ++k) {
    e[1 + k] = fenc(d[k]);
    e[7 + k] = fenc(-d[k]);
  }
#pragma unroll
  for (int off = 32; off > 0; off >>= 1) {
#pragma unroll
    for (int k = 0; k < 13; ++k) {
      unsigned o = (unsigned)__shfl_xor((int)e[k], off);
      e[k] = e[k] > o ? e[k] : o;
    }
  }
  __shared__ unsigned shu[4][13];
  if (lane == 0) {
#pragma unroll
    for (int k = 0; k < 13; ++k) shu[wave][k] = e[k];
  }
  __syncthreads();
  if (t < 13) {
    unsigned v = shu[0][t];
#pragma unroll
    for (int wv = 1; wv < 4; ++wv) v = v > shu[wv][t] ? v : shu[wv][t];
    RMAX[bx * 16 + t] = v;
  }
}

// ==== K2: s/eps0 + pack AREC/Qarr + moment-1 partial =======================
__global__ __launch_bounds__(256) void k2_pack(
    const float* __restrict__ x, const float* __restrict__ y,
    float* __restrict__ w) {
  const int t = threadIdx.x, wave = t >> 6, lane = t & 63, bx = blockIdx.x;
  const unsigned* RMAX = (const unsigned*)w + 64;
  float* MOMP1 = w + 2560;
  float* base = w + 16384;
  uint4* AREC = (uint4*)base;
  float* Qarr = base + 3 * 4 * PTS_TOTAL;

  __shared__ unsigned shu[4][13];
  __shared__ float shf[4][28];
  float s, eps0;
  se_from_rmax(RMAX, shu, s, eps0, t, wave, lane);

  const int g = bx * 256 + t;
  const int side = g >> 14;
  const float* p = (side ? y : x) + (size_t)(g & (ROWS - 1)) * 6;
  float v[6]; float q = mkv(p, s, v);
  Qarr[g] = q;
  unsigned w01 = pkh2(v[0], v[1]), w23 = pkh2(v[2], v[3]), w45 = pkh2(v[4], v[5]);
  AREC[g] = (uint4){w01, w23, w45, pkh2(1.0f, 0.0f)};

  float wgt = fexp2(NEG_LOG2M - q * (LOG2E / eps0));
  float acc[28];
  mom28(acc, wgt, v);
  red28g(acc, MOMP1 + (size_t)bx * 32, shf, t, wave, lane);
}

// ==== K3: M1opp -> f1 (FG1) + moment-2 partial =============================
__global__ __launch_bounds__(256) void k3_rows1(
    const float* __restrict__ x, const float* __restrict__ y,
    float* __restrict__ w) {
  const int t = threadIdx.x, wave = t >> 6, lane = t & 63, bx = blockIdx.x;
  const unsigned* RMAX = (const unsigned*)w + 64;
  const float* MOMP1 = w + 2560;
  float* MOMP2 = w + 2560 + 4096;
  float* base = w + 16384;
  float* FG1 = base + 3 * 4 * PTS_TOTAL + PTS_TOTAL + PTS_TOTAL;  // after Qarr,FG2

  __shared__ unsigned shu[4][13];
  __shared__ float shf[4][28];
  __shared__ float M1opp[28];
  float s, eps0;
  se_from_rmax(RMAX, shu, s, eps0, t, wave, lane);

  const int g = bx * 256 + t;
  const int side = g >> 14;
  const int batch = (g >> 12) & 3;
  if (t < 28) {
    const float* mp = MOMP1 + ((size_t)((side ^ 1) * 64 + batch * 16)) * 32 + t;
    float m = 0.0f;
#pragma unroll
    for (int j = 0; j < 16; ++j) m += mp[j * 32];
    M1opp[t] = m;
  }
  __syncthreads();

  const float* p = (side ? y : x) + (size_t)(g & (ROWS - 1)) * 6;
  float v[6]; float q = mkv(p, s, v);
  float f1 = taylor_f(M1opp, v, q, eps0);
  FG1[g] = f1;
  float w2 = fexp2(NEG_LOG2M + (f1 - q) * (LOG2E / eps0));
  float acc[28];
  mom28(acc, w2, v);
  red28g(acc, MOMP2 + (size_t)bx * 32, shf, t, wave, lane);
}

// ==== K4: M2opp -> f2 (FG2) + BRECA with hs2 ===============================
__global__ __launch_bounds__(256) void k4_rows2(
    const float* __restrict__ x, const float* __restrict__ y,
    float* __restrict__ w) {
  const int t = threadIdx.x, wave = t >> 6, lane = t & 63, bx = blockIdx.x;
  const unsigned* RMAX = (const unsigned*)w + 64;
  const float* MOMP2 = w + 2560 + 4096;
  float* base = w + 16384;
  uint4* BRECA = (uint4*)base + PTS_TOTAL;
  float* Qarr = base + 3 * 4 * PTS_TOTAL;
  float* FG2 = Qarr + PTS_TOTAL;
  const float* FG1 = FG2 + PTS_TOTAL;

  __shared__ unsigned shu[4][13];
  __shared__ float M2opp[28];
  float s, eps0;
  se_from_rmax(RMAX, shu, s, eps0, t, wave, lane);

  const int g = bx * 256 + t;
  const int side = g >> 14;
  const int batch = (g >> 12) & 3;
  if (t < 28) {
    const float* mp = MOMP2 + ((size_t)((side ^ 1) * 64 + batch * 16)) * 32 + t;
    float m = 0.0f;
#pragma unroll
    for (int j = 0; j < 16; ++j) m += mp[j * 32];
    M2opp[t] = m;
  }
  __syncthreads();

  const float* p = (side ? y : x) + (size_t)(g & (ROWS - 1)) * 6;
  float v[6]; float q = mkv(p, s, v);
  float f1 = FG1[g];
  float f_t = taylor_f(M2opp, v, q, eps0);
  float f2 = 0.5f * (f1 + f_t);
  FG2[g] = f2;
  float hs2 = 0.5f * (f2 - q - EPS1LNM);
  unsigned w01 = pkh2(v[0], v[1]), w23 = pkh2(v[2], v[3]), w45 = pkh2(v[4], v[5]);
  BRECA[g] = (uint4){w01, w23, w45, pkh2(hs2, 0.0f)};
}

// ---- XCD-aware remap: 256 = 32 x 8 (kept from R12; null but harmless) -----
__device__ inline int xcd_rowgrp(int bx) {
  return (bx & 7) * 32 + (bx >> 3);
}

// ---- BARRIER-FREE wave-private softmin: 128 rows/block, 8 waves. Each wave
// stages ITS OWN 512-record column slice into its own LDS region and consumes
// only that slice -> no block-wide stage->sync->compute serialization. Waves
// self-stagger: while one waits on its 8 staging loads, others run their
// 256-MFMA loops. One final __syncthreads merges per-wave row maxes.
__device__ inline float softmax_wp128(int grow0,
                                      const uint4* __restrict__ AREC,
                                      const uint4* __restrict__ BIN,
                                      uint4* __restrict__ Blds,
                                      float (*lm)[128]) {
  int t = threadIdx.x;
  int w = t >> 6, lane = t & 63;
  int l16 = lane & 15;
  bool ldq = lane < 16;                       // quad 0 carries k=0..7
  int side = grow0 >> 14;
  int batch = (grow0 & (ROWS - 1)) >> 12;
  int panel0 = (side ^ 1) * ROWS + batch * 4096;

  // ---- wave-private stage: wave w owns records [w*512, (w+1)*512) ----
  const uint4* gsrc = BIN + panel0 + w * 512 + lane;
  uint4* ldst = Blds + w * 512 + lane;
  uint4 s0 = gsrc[0],   s1 = gsrc[64],  s2 = gsrc[128], s3 = gsrc[192];
  uint4 s4 = gsrc[256], s5 = gsrc[320], s6 = gsrc[384], s7 = gsrc[448];

  // A fragments: 8 x 16-row tiles covering all 128 rows (named regs)
  uint4 z4 = (uint4){0u, 0u, 0u, 0u};
  uint4 a0u = z4, a1u = z4, a2u = z4, a3u = z4;
  uint4 a4u = z4, a5u = z4, a6u = z4, a7u = z4;
  if (ldq) {
    a0u = AREC[grow0 + l16];        a1u = AREC[grow0 + 16 + l16];
    a2u = AREC[grow0 + 32 + l16];   a3u = AREC[grow0 + 48 + l16];
    a4u = AREC[grow0 + 64 + l16];   a5u = AREC[grow0 + 80 + l16];
    a6u = AREC[grow0 + 96 + l16];   a7u = AREC[grow0 + 112 + l16];
  }
  v8h a0 = bcv8(a0u), a1 = bcv8(a1u), a2 = bcv8(a2u), a3 = bcv8(a3u);
  v8h a4 = bcv8(a4u), a5 = bcv8(a5u), a6 = bcv8(a6u), a7 = bcv8(a7u);

  ldst[0] = s0;   ldst[64] = s1;  ldst[128] = s2; ldst[192] = s3;
  ldst[256] = s4; ldst[320] = s5; ldst[384] = s6; ldst[448] = s7;
  // wave-local drain of this wave's ds_writes; no block barrier needed
  asm volatile("s_waitcnt lgkmcnt(0)" ::: "memory");

  f32x4 m0 = {-3.0e38f, -3.0e38f, -3.0e38f, -3.0e38f};
  f32x4 m1 = m0, m2 = m0, m3 = m0, m4 = m0, m5 = m0, m6 = m0, m7 = m0;
  const f32x4 cz = {0.0f, 0.0f, 0.0f, 0.0f};
  const int col0 = w * 512;                   // own slice only

#pragma unroll 4
  for (int tt = 0; tt < 32; ++tt) {
    uint4 bu = z4;
    if (ldq) bu = Blds[col0 + tt * 16 + l16];
    v8h b = bcv8(bu);
    f32x4 d0 = __builtin_amdgcn_mfma_f32_16x16x32_f16(a0, b, cz, 0, 0, 0);
    f32x4 d1 = __builtin_amdgcn_mfma_f32_16x16x32_f16(a1, b, cz, 0, 0, 0);
    f32x4 d2 = __builtin_amdgcn_mfma_f32_16x16x32_f16(a2, b, cz, 0, 0, 0);
    f32x4 d3 = __builtin_amdgcn_mfma_f32_16x16x32_f16(a3, b, cz, 0, 0, 0);
    m0 = __builtin_elementwise_max(m0, d0);
    m1 = __builtin_elementwise_max(m1, d1);
    m2 = __builtin_elementwise_max(m2, d2);
    m3 = __builtin_elementwise_max(m3, d3);
    f32x4 d4 = __builtin_amdgcn_mfma_f32_16x16x32_f16(a4, b, cz, 0, 0, 0);
    f32x4 d5 = __builtin_amdgcn_mfma_f32_16x16x32_f16(a5, b, cz, 0, 0, 0);
    f32x4 d6 = __builtin_amdgcn_mfma_f32_16x16x32_f16(a6, b, cz, 0, 0, 0);
    f32x4 d7 = __builtin_amdgcn_mfma_f32_16x16x32_f16(a7, b, cz, 0, 0, 0);
    m4 = __builtin_elementwise_max(m4, d4);
    m5 = __builtin_elementwise_max(m5, d5);
    m6 = __builtin_elementwise_max(m6, d6);
    m7 = __builtin_elementwise_max(m7, d7);
  }

  // reduce over the 16 col-lanes (C/D: col=lane&15, row=quad*4+reg)
#pragma unroll
  for (int off = 1; off <= 8; off <<= 1) {
#pragma unroll
    for (int r = 0; r < 4; ++r) {
      m0[r] = fmaxf(m0[r], __shfl_xor(m0[r], off));
      m1[r] = fmaxf(m1[r], __shfl_xor(m1[r], off));
      m2[r] = fmaxf(m2[r], __shfl_xor(m2[r], off));
      m3[r] = fmaxf(m3[r], __shfl_xor(m3[r], off));
      m4[r] = fmaxf(m4[r], __shfl_xor(m4[r], off));
      m5[r] = fmaxf(m5[r], __shfl_xor(m5[r], off));
      m6[r] = fmaxf(m6[r], __shfl_xor(m6[r], off));
      m7[r] = fmaxf(m7[r], __shfl_xor(m7[r], off));
    }
  }
  if (l16 == 0) {
    int qd = lane >> 4;
#pragma unroll
    for (int r = 0; r < 4; ++r) {
      lm[w][qd * 4 + r]       = m0[r];
      lm[w][16 + qd * 4 + r]  = m1[r];
      lm[w][32 + qd * 4 + r]  = m2[r];
      lm[w][48 + qd * 4 + r]  = m3[r];
      lm[w][64 + qd * 4 + r]  = m4[r];
      lm[w][80 + qd * 4 + r]  = m5[r];
      lm[w][96 + qd * 4 + r]  = m6[r];
      lm[w][112 + qd * 4 + r] = m7[r];
    }
  }
  __syncthreads();                            // single barrier: merge waves
  float m = 0.0f;
  if (t < 128) {
    float ma = fmaxf(fmaxf(lm[0][t], lm[1][t]), fmaxf(lm[2][t], lm[3][t]));
    float mb = fmaxf(fmaxf(lm[4][t], lm[5][t]), fmaxf(lm[6][t], lm[7][t]));
    m = fmaxf(ma, mb);
  }
  return m;
}

// ==== KB: eps1 softmin pair-3 -> BRECB =====================================
__global__ __launch_bounds__(512) void kb_sm1(
    const uint4* __restrict__ AREC, const uint4* __restrict__ BIN,
    uint4* __restrict__ BOUT, const float* __restrict__ Qarr,
    const float* __restrict__ FG2) {
  __shared__ uint4 Blds[4096];
  __shared__ float lm[8][128];
  int t = threadIdx.x;
  int grow0 = xcd_rowgrp(blockIdx.x) * 128;
  // prefetch epilogue operands; latency hides under staging + MFMA loop
  float qv = 0.0f, fprev = 0.0f;
  uint4 ar = (uint4){0u, 0u, 0u, 0u};
  if (t < 128) {
    int gg = grow0 + t;
    qv = Qarr[gg];
    fprev = FG2[gg];
    ar = AREC[gg];
  }
  float m = softmax_wp128(grow0, AREC, BIN, Blds, lm);
  if (t < 128) {
    float f_t = qv - 2.0f * m;
    float fo = 0.5f * (fprev + f_t);
    float hs = 0.5f * (fo - qv - EPS1LNM);
    BOUT[grow0 + t] = (uint4){ar.x, ar.y, ar.z, pkh2(hs, 0.0f)};
  }
}

// ==== KC: eps1 softmin pair-4 + dynamic last-block collector ===============
__global__ __launch_bounds__(512) void kc_sm2(
    const uint4* __restrict__ AREC, const uint4* __restrict__ BIN,
    const float* __restrict__ Qarr, float* __restrict__ PART,
    unsigned* __restrict__ BARC, float* __restrict__ out) {
  __shared__ uint4 Blds[4096];
  __shared__ float lm[8][128];
  __shared__ float fsh[128];
  __shared__ float fred[8];
  __shared__ int lastf;
  int t = threadIdx.x;
  int wave = t >> 6, lane = t & 63;
  int grow0 = xcd_rowgrp(blockIdx.x) * 128;
  float qv = 0.0f;
  if (t < 128) qv = Qarr[grow0 + t];
  float m = softmax_wp128(grow0, AREC, BIN, Blds, lm);
  if (t < 128) fsh[t] = qv - 2.0f * m;
  __syncthreads();
  if (t == 0) {
    float ssum = 0.0f;
#pragma unroll
    for (int k = 0; k < 128; ++k) ssum += fsh[k];
    __hip_atomic_store(&PART[blockIdx.x], ssum, __ATOMIC_RELAXED,
                       __HIP_MEMORY_SCOPE_AGENT);
    unsigned old = __hip_atomic_fetch_add(BARC, 1u, __ATOMIC_ACQ_REL,
                                          __HIP_MEMORY_SCOPE_AGENT);
    lastf = (old == (unsigned)(NSM_BLK - 1)) ? 1 : 0;
  }
  __syncthreads();
  if (lastf) {  // block-uniform: only the final arriver sums and writes out
    float a = 0.0f;
    if (t < NSM_BLK)
      a = __hip_atomic_load(&PART[t], __ATOMIC_RELAXED,
                            __HIP_MEMORY_SCOPE_AGENT);
#pragma unroll
    for (int off = 32; off > 0; off >>= 1) a += __shfl_xor(a, off);
    if (lane == 0) fred[wave] = a;
    __syncthreads();
    if (t == 0) {
      float s8 = 0.0f;
#pragma unroll
      for (int k = 0; k < 8; ++k) s8 += fred[k];
      out[0] = s8 * (10.0f / (float)ROWS);
    }
  }
}

extern "C" void kernel_launch(void* const* d_in, const int* in_sizes, int n_in,
                              void* d_out, int out_size, void* d_ws,
                              size_t ws_size, hipStream_t stream) {
  const float* x = (const float*)d_in[0];
  const float* y = (const float*)d_in[1];
  float* out = (float*)d_out;
  float* w = (float*)d_ws;

  unsigned* BARC = (unsigned*)w;
  float* base = w + 16384;
  uint4* AREC  = (uint4*)base;
  uint4* BRECA = AREC + PTS_TOTAL;
  uint4* BRECB = BRECA + PTS_TOTAL;
  float* Qarr  = base + 3 * 4 * PTS_TOTAL;
  float* FG2   = Qarr + PTS_TOTAL;
  float* FG1   = FG2 + PTS_TOTAL;
  float* PART  = FG1 + PTS_TOTAL;

  (void)ws_size;
  k1_max<<<128, 256, 0, stream>>>(x, y, w);
  k2_pack<<<128, 256, 0, stream>>>(x, y, w);
  k3_rows1<<<128, 256, 0, stream>>>(x, y, w);
  k4_rows2<<<128, 256, 0, stream>>>(x, y, w);
  kb_sm1<<<NSM_BLK, 512, 0, stream>>>(AREC, BRECA, BRECB, Qarr, FG2);
  kc_sm2<<<NSM_BLK, 512, 0, stream>>>(AREC, BRECB, Qarr, PART, BARC, out);
}